// Round 7
// baseline (57.966 us; speedup 1.0000x reference)
//
#include <hip/hip_runtime.h>
#include <hip/hip_bf16.h>
#include <stdint.h>

typedef __attribute__((ext_vector_type(8))) short short8;
typedef __attribute__((ext_vector_type(4))) float f32x4;

#define BSZ 512
#define KTOT 49152
#define KSPLIT 96
#define KCHUNK 512
#define BK 64
#define NKSTEP (KCHUNK / BK)   /* 8 */
#define NTILE 10
#define TSIZE (128 * 128)
#define SKEW 5
#define NPAIRS 130816.0f

__device__ __forceinline__ float bf2f(ushort u) {
    return __uint_as_float(((uint32_t)u) << 16);
}

__device__ __forceinline__ ushort f2bf(float f) {
    uint32_t u = __float_as_uint(f);
    uint32_t r = (u + 0x7fffu + ((u >> 16) & 1u)) >> 16;
    return (ushort)r;
}

__device__ __forceinline__ uint2 cvt_f4(float4 v) {
    uint2 r;
    asm("v_cvt_pk_bf16_f32 %0, %1, %2" : "=v"(r.x) : "v"(v.x), "v"(v.y));
    asm("v_cvt_pk_bf16_f32 %0, %1, %2" : "=v"(r.y) : "v"(v.z), "v"(v.w));
    return r;
}

__device__ __forceinline__ void gload_lds16(const ushort* g, ushort* l) {
    __builtin_amdgcn_global_load_lds(
        (const __attribute__((address_space(1))) uint32_t*)g,
        (__attribute__((address_space(3))) uint32_t*)l, 16, 0, 0);
}

// ---- Pass 1: fp32 fields -> single bf16 matrix W[512][49152] ----
__global__ __launch_bounds__(256) void convert_kernel(
    const float* __restrict__ e, const float* __restrict__ a,
    const float* __restrict__ c, ushort* __restrict__ W) {
    const int g = blockIdx.x * 256 + threadIdx.x;   // 12288 blocks
    const int E = g * 8;
    const int f = E >> 23;
    const int rem = E & 8388607;
    const int row = rem >> 14, col = rem & 16383;
    const float* src = (f == 0) ? e : (f == 1 ? a : c);
    float4 v0 = reinterpret_cast<const float4*>(src + rem)[0];
    float4 v1 = reinterpret_cast<const float4*>(src + rem)[1];
    uint2 w0 = cvt_f4(v0), w1 = cvt_f4(v1);
    uint4 w = {w0.x, w0.y, w1.x, w1.y};
    *reinterpret_cast<uint4*>(&W[(size_t)row * KTOT + f * 16384 + col]) = w;
}

// ---- Pass 2: m97-structure GEMM, KSPLIT=96.
// XCD co-location: all 10 tiles of one ks land on one XCD (same L2) at the
// same time -> each 512 KB panel-slice fetched from L3 once, reused 4x.
__global__ __launch_bounds__(256, 4) void gemm_kernel(
    const ushort* __restrict__ W, ushort* __restrict__ P) {
    const int b = blockIdx.x;                // 960 blocks
    const int x = b & 7, g = b >> 3;         // x = XCD (round-robin dispatch)
    const int tile = g % 10;
    const int ks   = (g / 10) * 8 + x;       // same ks -> same XCD, consecutive
    int ti = 0, rem = tile;
    while (rem >= 4 - ti) { rem -= 4 - ti; ++ti; }
    const int tj = ti + rem;
    const bool diag = (ti == tj);
    const int brow = ti * 128, bcol = tj * 128;
    const int kbase = ks * KCHUNK;

    __shared__ ushort As[128 * 64];
    __shared__ ushort Bs[128 * 64];

    const int t = threadIdx.x;
    const int lane = t & 63, wid = t >> 6;
    const int wr = (wid >> 1) * 64, wc = (wid & 1) * 64;
    const bool skipw = diag && (wr == 64) && (wc == 0);

    // staging: linear LDS dest + pre-swizzled per-lane global source (rule #21)
    const int grow = t >> 3, s = t & 7;
    const int swz = (s ^ (grow & 7)) * 8;
    const ushort* pa = W + (size_t)(brow + grow) * KTOT + kbase + swz;
    const ushort* pb = W + (size_t)(bcol + grow) * KTOT + kbase + swz;
    ushort* la = &As[t * 8];
    ushort* lb = &Bs[t * 8];

    const f32x4 zero = {0.f, 0.f, 0.f, 0.f};
    f32x4 acc[4][4];
#pragma unroll
    for (int m = 0; m < 4; ++m)
#pragma unroll
        for (int n = 0; n < 4; ++n) acc[m][n] = zero;

#pragma unroll 1
    for (int kt = 0; kt < NKSTEP; ++kt) {
        const int kk = kt * BK;
#pragma unroll
        for (int i = 0; i < 4; ++i)
            gload_lds16(pa + (size_t)(i * 32) * KTOT + kk, la + i * 2048);
        if (!diag) {
#pragma unroll
            for (int i = 0; i < 4; ++i)
                gload_lds16(pb + (size_t)(i * 32) * KTOT + kk, lb + i * 2048);
        }
        __syncthreads();
        if (!skipw) {
            const ushort* Bsrc = diag ? As : Bs;
#pragma unroll
            for (int half = 0; half < 2; ++half) {
                short8 af[4], bfv[4];
                const int kq = half * 4 + (lane >> 4);
#pragma unroll
                for (int m = 0; m < 4; ++m) {
                    const int row = wr + m * 16 + (lane & 15);
                    const int gg = kq ^ (row & 7);
                    af[m] = *reinterpret_cast<const short8*>(&As[row * 64 + gg * 8]);
                }
#pragma unroll
                for (int n = 0; n < 4; ++n) {
                    const int row = wc + n * 16 + (lane & 15);
                    const int gg = kq ^ (row & 7);
                    bfv[n] = *reinterpret_cast<const short8*>(&Bsrc[row * 64 + gg * 8]);
                }
#pragma unroll
                for (int m = 0; m < 4; ++m)
#pragma unroll
                    for (int n = 0; n < 4; ++n)
                        acc[m][n] = __builtin_amdgcn_mfma_f32_16x16x32_bf16(
                            af[m], bfv[n], acc[m][n], 0, 0, 0);
            }
        }
        __syncthreads();
    }

    if (!skipw) {
        ushort* Pk = P + (size_t)(tile * KSPLIT + ks) * TSIZE;
        const int ci = (lane >> 4) * 4, cj = lane & 15;
#pragma unroll
        for (int m = 0; m < 4; ++m)
#pragma unroll
            for (int n = 0; n < 4; ++n)
#pragma unroll
                for (int r = 0; r < 4; ++r) {
                    const int li = wr + m * 16 + ci + r;
                    const int lj = wc + n * 16 + cj;
                    const int pr = (li + SKEW * ks) & 127;
                    Pk[pr * 128 + lj] = f2bf(acc[m][n][r]);
                }
    }
}

// Collapse 96 bf16 slices -> fp32 G[10][128][128]; DIAG inline. 320 blocks.
__global__ __launch_bounds__(256) void reducek_kernel(
    const ushort* __restrict__ P, float* __restrict__ G, float* __restrict__ DIAG) {
    const int t = threadIdx.x;
    const int tile  = blockIdx.x >> 5;   // 10 tiles x 32 chunks
    const int chunk = blockIdx.x & 31;
    const int li  = chunk * 4 + (t >> 6);
    const int ljq = (t & 63) * 2;
    float s0 = 0.f, s1 = 0.f;
    const ushort* base = P + (size_t)tile * KSPLIT * TSIZE + ljq;
#pragma unroll 8
    for (int k = 0; k < KSPLIT; ++k) {
        const int pr = (li + SKEW * k) & 127;
        const uint v = *reinterpret_cast<const uint*>(base + (size_t)k * TSIZE + pr * 128);
        s0 += bf2f((ushort)(v & 0xffff));
        s1 += bf2f((ushort)(v >> 16));
    }
    float2 g = {s0, s1};
    *reinterpret_cast<float2*>(&G[(size_t)tile * TSIZE + li * 128 + ljq]) = g;
    int dti = -1;
    if (tile == 0) dti = 0; else if (tile == 4) dti = 1;
    else if (tile == 7) dti = 2; else if (tile == 9) dti = 3;
    if (dti >= 0 && ljq == (li & ~1))
        DIAG[dti * 128 + li] = (li & 1) ? s1 : s0;
}

__global__ __launch_bounds__(256) void pair_kernel(
    const float* __restrict__ G, const float* __restrict__ DIAG,
    const int* __restrict__ tg, float* __restrict__ LP) {
    const int t = threadIdx.x;
    const int gid = blockIdx.x * 256 + t;   // 128 blocks
    const int i = gid >> 6;
    const int j0 = (gid & 63) * 8;
    float local = 0.f;
    if (j0 + 7 > i) {
        const int ti2 = i >> 7, tj2 = j0 >> 7;
        const int tidx = (ti2 * (9 - ti2)) / 2 + (tj2 - ti2);
        const int li = i & 127, lj0 = j0 & 127;
        const float* g = G + (size_t)tidx * TSIZE + li * 128 + lj0;
        float4 g0 = reinterpret_cast<const float4*>(g)[0];
        float4 g1 = reinterpret_cast<const float4*>(g)[1];
        float gv[8] = {g0.x, g0.y, g0.z, g0.w, g1.x, g1.y, g1.z, g1.w};
        const float di = DIAG[i];
        const int lbl = tg[i];
#pragma unroll
        for (int u = 0; u < 8; ++u) {
            const int j = j0 + u;
            if (j > i) {
                const float d = (di + DIAG[j] - 2.f * gv[u]) * (1.f / 16384.f);
                local += (lbl == tg[j]) ? d : fmaxf(1.f - d, 0.f);
            }
        }
    }
#pragma unroll
    for (int off = 32; off; off >>= 1) local += __shfl_down(local, off, 64);
    __shared__ float red[4];
    const int lane = t & 63, wid = t >> 6;
    if (lane == 0) red[wid] = local;
    __syncthreads();
    if (t == 0) LP[blockIdx.x] = red[0] + red[1] + red[2] + red[3];
}

__global__ void final_kernel(const float* __restrict__ LP, float* __restrict__ out) {
    const int t = threadIdx.x;  // 128
    float v = LP[t];
#pragma unroll
    for (int off = 32; off; off >>= 1) v += __shfl_down(v, off, 64);
    __shared__ float red[2];
    if ((t & 63) == 0) red[t >> 6] = v;
    __syncthreads();
    if (t == 0) out[0] = (red[0] + red[1]) * (1.f / NPAIRS);
}

extern "C" void kernel_launch(void* const* d_in, const int* in_sizes, int n_in,
                              void* d_out, int out_size, void* d_ws, size_t ws_size,
                              hipStream_t stream) {
    const float* e  = (const float*)d_in[0];
    const float* a  = (const float*)d_in[1];
    const float* c  = (const float*)d_in[2];
    const int*   tg = (const int*)d_in[3];

    ushort* W    = (ushort*)d_ws;                                  // 50.33 MB
    ushort* P    = W + (size_t)BSZ * KTOT;                         // 31.46 MB
    float*  G    = (float*)(P + (size_t)NTILE * KSPLIT * TSIZE);   // 0.66 MB
    float*  DIAG = G + (size_t)NTILE * TSIZE;
    float*  LP   = DIAG + BSZ;
    float*  out  = (float*)d_out;

    convert_kernel<<<dim3(12288), dim3(256), 0, stream>>>(e, a, c, W);
    gemm_kernel<<<dim3(NTILE * KSPLIT), dim3(256), 0, stream>>>(W, P);
    reducek_kernel<<<dim3(320), dim3(256), 0, stream>>>(P, G, DIAG);
    pair_kernel<<<dim3(128), dim3(256), 0, stream>>>(G, DIAG, tg, LP);
    final_kernel<<<dim3(1), dim3(128), 0, stream>>>(LP, out);
}

// Round 8
// 47.371 us; speedup vs baseline: 1.2237x; 1.2237x over previous
//
#include <hip/hip_runtime.h>
#include <hip/hip_bf16.h>
#include <stdint.h>

typedef __attribute__((ext_vector_type(4))) float f32x4;
typedef __attribute__((ext_vector_type(2))) unsigned long long ull2;

#define BSZ 512
#define KTOT 49152
#define KSPLIT 48
#define KCHUNK 1024            /* fp8 elements per K-slice */
#define BK 128                 /* fp8 elements per K-step (128 B/row) */
#define NKSTEP (KCHUNK / BK)   /* 8 */
#define NTILE 10
#define TSIZE (128 * 128)
#define SKEW 5
#define NPAIRS 130816.0f

__device__ __forceinline__ float bf2f(ushort u) {
    return __uint_as_float(((uint32_t)u) << 16);
}

__device__ __forceinline__ ushort f2bf(float f) {
    uint32_t u = __float_as_uint(f);
    uint32_t r = (u + 0x7fffu + ((u >> 16) & 1u)) >> 16;
    return (ushort)r;
}

__device__ __forceinline__ void gload_lds16(const uint8_t* g, uint8_t* l) {
    __builtin_amdgcn_global_load_lds(
        (const __attribute__((address_space(1))) uint32_t*)g,
        (__attribute__((address_space(3))) uint32_t*)l, 16, 0, 0);
}

// ---- Pass 1: fp32 fields -> fp8 e4m3 matrix W[512][49152], PERMUTED:
// logical k = 64H + 32s + 8q + b  ->  phys byte = 64H + 16q + 8s + b
// so a GEMM lane's 16B granule read = (MFMA k-sub0 operand, k-sub1 operand).
__global__ __launch_bounds__(256) void convert_kernel(
    const float* __restrict__ e, const float* __restrict__ a,
    const float* __restrict__ c, uint8_t* __restrict__ W) {
    const int g = blockIdx.x * 256 + threadIdx.x;   // 12288 blocks
    const int E = g * 8;
    const int f = E >> 23;                          // field (8388608 elems)
    const int rem = E & 8388607;
    const int row = rem >> 14, col = rem & 16383;
    const float* src = (f == 0) ? e : (f == 1 ? a : c);
    float4 v0 = reinterpret_cast<const float4*>(src + rem)[0];
    float4 v1 = reinterpret_cast<const float4*>(src + rem)[1];
    uint lo = __builtin_amdgcn_cvt_pk_fp8_f32(v0.x, v0.y, 0, false);
    lo = __builtin_amdgcn_cvt_pk_fp8_f32(v0.z, v0.w, lo, true);
    uint hi = __builtin_amdgcn_cvt_pk_fp8_f32(v1.x, v1.y, 0, false);
    hi = __builtin_amdgcn_cvt_pk_fp8_f32(v1.z, v1.w, hi, true);
    const int k = f * 16384 + col;                  // 8-aligned
    const int H = k >> 6, s = (k >> 5) & 1, q = (k >> 3) & 3;
    const size_t phys = (size_t)row * KTOT + H * 64 + q * 16 + s * 8;
    uint2 w = {lo, hi};
    *reinterpret_cast<uint2*>(&W[phys]) = w;
}

// ---- Pass 2: m97-structure fp8 GEMM. 128^2 upper-tri tiles, KSPLIT=48,
// global_load_lds w=16, linear LDS dest + pre-swizzled source + swizzled
// b128 fragment reads (identical addressing to the proven bf16 kernel). ----
__global__ __launch_bounds__(256, 2) void gemm_kernel(
    const uint8_t* __restrict__ W, ushort* __restrict__ P) {
    const int tile = blockIdx.x / KSPLIT;
    const int ks   = blockIdx.x % KSPLIT;
    int ti = 0, rem = tile;
    while (rem >= 4 - ti) { rem -= 4 - ti; ++ti; }
    const int tj = ti + rem;
    const bool diag = (ti == tj);
    const int brow = ti * 128, bcol = tj * 128;
    const int kbase = ks * KCHUNK;                  // byte == element

    __shared__ uint8_t As[128 * 128];
    __shared__ uint8_t Bs[128 * 128];

    const int t = threadIdx.x;
    const int lane = t & 63, wid = t >> 6;
    const int wr = (wid >> 1) * 64, wc = (wid & 1) * 64;
    const bool skipw = diag && (wr == 64) && (wc == 0);

    // staging: thread t covers (row-in-issue = t>>3, granule s = t&7);
    // source granule pre-swizzled by row so LDS[row][g] = Wrow[g ^ (row&7)].
    const int grow = t >> 3, s = t & 7;
    const int swz = (s ^ (grow & 7)) * 16;          // bytes
    const uint8_t* pa = W + (size_t)(brow + grow) * KTOT + kbase + swz;
    const uint8_t* pb = W + (size_t)(bcol + grow) * KTOT + kbase + swz;
    uint8_t* la = &As[t * 16];
    uint8_t* lb = &Bs[t * 16];

    const f32x4 zero = {0.f, 0.f, 0.f, 0.f};
    f32x4 acc[4][4];
#pragma unroll
    for (int m = 0; m < 4; ++m)
#pragma unroll
        for (int n = 0; n < 4; ++n) acc[m][n] = zero;

#pragma unroll 1
    for (int kt = 0; kt < NKSTEP; ++kt) {
        const int kk = kt * BK;
#pragma unroll
        for (int i = 0; i < 4; ++i)
            gload_lds16(pa + (size_t)(i * 32) * KTOT + kk, la + i * 4096);
        if (!diag) {
#pragma unroll
            for (int i = 0; i < 4; ++i)
                gload_lds16(pb + (size_t)(i * 32) * KTOT + kk, lb + i * 4096);
        }
        __syncthreads();
        if (!skipw) {
            const uint8_t* Bsrc = diag ? As : Bs;
#pragma unroll
            for (int half = 0; half < 2; ++half) {
                ull2 af[4], bfv[4];
                const int kq = half * 4 + (lane >> 4);
#pragma unroll
                for (int m = 0; m < 4; ++m) {
                    const int row = wr + m * 16 + (lane & 15);
                    const int gg = kq ^ (row & 7);
                    af[m] = *reinterpret_cast<const ull2*>(&As[row * 128 + gg * 16]);
                }
#pragma unroll
                for (int n = 0; n < 4; ++n) {
                    const int row = wc + n * 16 + (lane & 15);
                    const int gg = kq ^ (row & 7);
                    bfv[n] = *reinterpret_cast<const ull2*>(&Bsrc[row * 128 + gg * 16]);
                }
#pragma unroll
                for (int m = 0; m < 4; ++m)
#pragma unroll
                    for (int n = 0; n < 4; ++n) {
                        acc[m][n] = __builtin_amdgcn_mfma_f32_16x16x32_fp8_fp8(
                            (long long)af[m][0], (long long)bfv[n][0], acc[m][n], 0, 0, 0);
                        acc[m][n] = __builtin_amdgcn_mfma_f32_16x16x32_fp8_fp8(
                            (long long)af[m][1], (long long)bfv[n][1], acc[m][n], 0, 0, 0);
                    }
            }
        }
        __syncthreads();
    }

    if (!skipw) {
        ushort* Pk = P + (size_t)(tile * KSPLIT + ks) * TSIZE;
        const int ci = (lane >> 4) * 4, cj = lane & 15;
#pragma unroll
        for (int m = 0; m < 4; ++m)
#pragma unroll
            for (int n = 0; n < 4; ++n)
#pragma unroll
                for (int r = 0; r < 4; ++r) {
                    const int li = wr + m * 16 + ci + r;
                    const int lj = wc + n * 16 + cj;
                    const int pr = (li + SKEW * ks) & 127;
                    Pk[pr * 128 + lj] = f2bf(acc[m][n][r]);
                }
    }
}

// Collapse 48 bf16 slices -> fp32 G[10][128][128]; DIAG inline. 320 blocks.
__global__ __launch_bounds__(256) void reducek_kernel(
    const ushort* __restrict__ P, float* __restrict__ G, float* __restrict__ DIAG) {
    const int t = threadIdx.x;
    const int tile  = blockIdx.x >> 5;   // 10 tiles x 32 chunks
    const int chunk = blockIdx.x & 31;
    const int li  = chunk * 4 + (t >> 6);
    const int ljq = (t & 63) * 2;
    float s0 = 0.f, s1 = 0.f;
    const ushort* base = P + (size_t)tile * KSPLIT * TSIZE + ljq;
#pragma unroll 8
    for (int k = 0; k < KSPLIT; ++k) {
        const int pr = (li + SKEW * k) & 127;
        const uint v = *reinterpret_cast<const uint*>(base + (size_t)k * TSIZE + pr * 128);
        s0 += bf2f((ushort)(v & 0xffff));
        s1 += bf2f((ushort)(v >> 16));
    }
    float2 g = {s0, s1};
    *reinterpret_cast<float2*>(&G[(size_t)tile * TSIZE + li * 128 + ljq]) = g;
    int dti = -1;
    if (tile == 0) dti = 0; else if (tile == 4) dti = 1;
    else if (tile == 7) dti = 2; else if (tile == 9) dti = 3;
    if (dti >= 0 && ljq == (li & ~1))
        DIAG[dti * 128 + li] = (li & 1) ? s1 : s0;
}

__global__ __launch_bounds__(256) void pair_kernel(
    const float* __restrict__ G, const float* __restrict__ DIAG,
    const int* __restrict__ tg, float* __restrict__ LP) {
    const int t = threadIdx.x;
    const int gid = blockIdx.x * 256 + t;   // 128 blocks
    const int i = gid >> 6;
    const int j0 = (gid & 63) * 8;
    float local = 0.f;
    if (j0 + 7 > i) {
        const int ti2 = i >> 7, tj2 = j0 >> 7;
        const int tidx = (ti2 * (9 - ti2)) / 2 + (tj2 - ti2);
        const int li = i & 127, lj0 = j0 & 127;
        const float* g = G + (size_t)tidx * TSIZE + li * 128 + lj0;
        float4 g0 = reinterpret_cast<const float4*>(g)[0];
        float4 g1 = reinterpret_cast<const float4*>(g)[1];
        float gv[8] = {g0.x, g0.y, g0.z, g0.w, g1.x, g1.y, g1.z, g1.w};
        const float di = DIAG[i];
        const int lbl = tg[i];
#pragma unroll
        for (int u = 0; u < 8; ++u) {
            const int j = j0 + u;
            if (j > i) {
                const float d = (di + DIAG[j] - 2.f * gv[u]) * (1.f / 16384.f);
                local += (lbl == tg[j]) ? d : fmaxf(1.f - d, 0.f);
            }
        }
    }
#pragma unroll
    for (int off = 32; off; off >>= 1) local += __shfl_down(local, off, 64);
    __shared__ float red[4];
    const int lane = t & 63, wid = t >> 6;
    if (lane == 0) red[wid] = local;
    __syncthreads();
    if (t == 0) LP[blockIdx.x] = red[0] + red[1] + red[2] + red[3];
}

__global__ void final_kernel(const float* __restrict__ LP, float* __restrict__ out) {
    const int t = threadIdx.x;  // 128
    float v = LP[t];
#pragma unroll
    for (int off = 32; off; off >>= 1) v += __shfl_down(v, off, 64);
    __shared__ float red[2];
    if ((t & 63) == 0) red[t >> 6] = v;
    __syncthreads();
    if (t == 0) out[0] = (red[0] + red[1]) * (1.f / NPAIRS);
}

extern "C" void kernel_launch(void* const* d_in, const int* in_sizes, int n_in,
                              void* d_out, int out_size, void* d_ws, size_t ws_size,
                              hipStream_t stream) {
    const float* e  = (const float*)d_in[0];
    const float* a  = (const float*)d_in[1];
    const float* c  = (const float*)d_in[2];
    const int*   tg = (const int*)d_in[3];

    uint8_t* W   = (uint8_t*)d_ws;                                 // 25.17 MB
    ushort* P    = (ushort*)(W + (size_t)BSZ * KTOT);              // 15.73 MB
    float*  G    = (float*)(P + (size_t)NTILE * KSPLIT * TSIZE);   // 0.66 MB
    float*  DIAG = G + (size_t)NTILE * TSIZE;
    float*  LP   = DIAG + BSZ;
    float*  out  = (float*)d_out;

    convert_kernel<<<dim3(12288), dim3(256), 0, stream>>>(e, a, c, W);
    gemm_kernel<<<dim3(NTILE * KSPLIT), dim3(256), 0, stream>>>(W, P);
    reducek_kernel<<<dim3(320), dim3(256), 0, stream>>>(P, G, DIAG);
    pair_kernel<<<dim3(128), dim3(256), 0, stream>>>(G, DIAG, tg, LP);
    final_kernel<<<dim3(1), dim3(128), 0, stream>>>(LP, out);
}